// Round 3
// baseline (28409.644 us; speedup 1.0000x reference)
//
#include <hip/hip_runtime.h>

// GeneratorDecoder: 128-step LSTM (H=32) + gumbel-argmax head (P=7), B=32768.
// 4 lanes per batch element, gate rows interleaved mod 4. FP trajectory
// bit-identical to rounds 1/2. Round-3 fix: NO runtime indexing into register
// arrays (rule #20) — lg[q]/lg[q+4] extracted via compile-time ternary chains
// (v_cndmask), eliminating the scratch demotion that caused ~80 GB of phantom
// HBM traffic in rounds 1-2.

#define Hh 32
#define Pp 7
#define NDd 8
#define G4 128
#define WHH_S 40        // row stride: 8-bank skew between consecutive rows, 16B aligned
#define HBUF_S 36
#define OUT_S 56        // 8 steps * 7 floats, per-batch staging stride

// float-offset layout of the shared block (15872 floats = 63488 B)
#define OFF_WHH   0        // 128*40 = 5120
#define OFF_WIHB  5120     // 128*8  = 1024
#define OFF_WHEAD 6144     // 32*8   = 256
#define OFF_HBUF  6400     // 64*36  = 2304
#define OFF_OUTL  8704     // 64*56  = 3584   (aliased by W_init/b_init at setup)
#define OFF_OUTS  12288    // 64*56  = 3584
#define SMEM_F    15872
#define OFF_WINIT OFF_OUTL          // 32*40 = 1280 (init phase only)
#define OFF_BINIT (OFF_OUTL + 1280) // 32

__global__ __launch_bounds__(256, 2) void gen_decoder_kernel(
    const float* __restrict__ h_n, const float* __restrict__ c_n,
    const float* __restrict__ noise, const float* __restrict__ gumbel_u,
    const float* __restrict__ W_init, const float* __restrict__ b_init,
    const float* __restrict__ W_ih, const float* __restrict__ W_hh,
    const float* __restrict__ b_ih, const float* __restrict__ b_hh,
    const float* __restrict__ W_head, const float* __restrict__ b_head,
    const int* __restrict__ future_len, float* __restrict__ out, int B)
{
  __shared__ __align__(16) float sm[SMEM_F];

  const int tid = threadIdx.x;

  for (int i = tid; i < G4 * Hh; i += 256) {
    int r = i >> 5, k = i & 31;
    sm[OFF_WHH + r * WHH_S + k] = W_hh[i];
  }
  for (int i = tid; i < G4 * 8; i += 256) {
    int r = i >> 3, p = i & 7;
    sm[OFF_WIHB + i] = b_ih[r] + b_hh[r] + (p < 7 ? W_ih[r * 7 + p] : 0.f);
  }
  for (int i = tid; i < Hh * 8; i += 256) {
    int j = i >> 3, p = i & 7;
    sm[OFF_WHEAD + i] = (p < 7) ? W_head[p * Hh + j] : 0.f;
  }
  for (int i = tid; i < Hh * (Hh + NDd); i += 256) sm[OFF_WINIT + i] = W_init[i];
  if (tid < Hh) sm[OFF_BINIT + tid] = b_init[tid];
  __syncthreads();

  const int q  = tid & 3;
  const int bb = tid >> 2;
  const int b  = blockIdx.x * 64 + bb;
  const int T  = future_len[0];

  // ---- init: h0 = [h_n ; noise] @ W_init.T + b_init  (bit-identical order) ----
  {
    float x[Hh + NDd];
    const float4* hp = (const float4*)(h_n + (size_t)b * Hh);
#pragma unroll
    for (int i = 0; i < 8; i++) ((float4*)x)[i] = hp[i];
    const float4* nz = (const float4*)(noise + (size_t)b * NDd);
    ((float4*)x)[8] = nz[0];
    ((float4*)x)[9] = nz[1];
#pragma unroll
    for (int m = 0; m < 8; m++) {
      int j = q + 4 * m;
      float a = sm[OFF_BINIT + j];
      const float* wr = &sm[OFF_WINIT + j * (Hh + NDd)];
#pragma unroll
      for (int k = 0; k < Hh + NDd; k++) a = fmaf(wr[k], x[k], a);
      sm[OFF_HBUF + bb * HBUF_S + j] = a;
    }
  }
  float c[8];
#pragma unroll
  for (int m = 0; m < 8; m++) c[m] = c_n[(size_t)b * Hh + q + 4 * m];

  float bh0 = b_head[(q == 0) ? 0 : (q == 1) ? 1 : (q == 2) ? 2 : 3];
  float bh4 = (q < 3) ? b_head[(q == 0) ? 4 : (q == 1) ? 5 : 6] : 0.f;

  // init phase used the OUT staging region for W_init -> barrier before reuse
  __syncthreads();

  int kcur = 7;  // y0 = 0 -> bias-only column
  const size_t strideT = (size_t)B * Pp;
  const float* gu = gumbel_u + (size_t)b * Pp;
  float* outL = out + (size_t)b * T * Pp;
  float* outS = out + (size_t)B * T * Pp + (size_t)b * T * Pp;

  for (int t = 0; t < T; ++t) {
    // gumbel inputs for this step (issue early)
    const float* ut = gu + (size_t)t * strideT;
    float u1 = ut[q];
    float u2 = (q < 3) ? ut[q + 4] : 1.f;

    // gate accumulators, init = column kcur of fused [W_ih | bias] table
    float acc[4][8];
#pragma unroll
    for (int s = 0; s < 4; s++)
#pragma unroll
      for (int m = 0; m < 8; m++)
        acc[s][m] = sm[OFF_WIHB + (s * Hh + q + 4 * m) * 8 + kcur];

    // stream h through float4 chunks; per-row k-order unchanged (ascending)
#pragma unroll
    for (int kc = 0; kc < 8; kc++) {
      float4 hv = *(const float4*)&sm[OFF_HBUF + bb * HBUF_S + 4 * kc];
#pragma unroll
      for (int s = 0; s < 4; s++)
#pragma unroll
        for (int m = 0; m < 8; m++) {
          float4 w = *(const float4*)&sm[OFF_WHH + (s * Hh + q + 4 * m) * WHH_S + 4 * kc];
          float a = acc[s][m];
          a = fmaf(w.x, hv.x, a);
          a = fmaf(w.y, hv.y, a);
          a = fmaf(w.z, hv.z, a);
          a = fmaf(w.w, hv.w, a);
          acc[s][m] = a;
        }
    }

    // elementwise LSTM cell
    float hnew[8];
#pragma unroll
    for (int m = 0; m < 8; m++) {
      float ig = 1.f / (1.f + expf(-acc[0][m]));
      float fg = 1.f / (1.f + expf(-acc[1][m]));
      float gg = tanhf(acc[2][m]);
      float og = 1.f / (1.f + expf(-acc[3][m]));
      float cc = fg * c[m] + ig * gg;
      c[m] = cc;
      hnew[m] = og * tanhf(cc);
    }
#pragma unroll
    for (int m = 0; m < 8; m++) sm[OFF_HBUF + bb * HBUF_S + q + 4 * m] = hnew[m];

    // head: partial logits over own slots, quad butterfly-sum (same order).
    // lg[] is ONLY ever statically indexed (no scratch demotion).
    float lg[8];
#pragma unroll
    for (int p = 0; p < 8; p++) lg[p] = 0.f;
#pragma unroll
    for (int m = 0; m < 8; m++) {
      float4 w0 = *(const float4*)&sm[OFF_WHEAD + (q + 4 * m) * 8];
      float4 w1 = *(const float4*)&sm[OFF_WHEAD + (q + 4 * m) * 8 + 4];
      lg[0] = fmaf(w0.x, hnew[m], lg[0]);
      lg[1] = fmaf(w0.y, hnew[m], lg[1]);
      lg[2] = fmaf(w0.z, hnew[m], lg[2]);
      lg[3] = fmaf(w0.w, hnew[m], lg[3]);
      lg[4] = fmaf(w1.x, hnew[m], lg[4]);
      lg[5] = fmaf(w1.y, hnew[m], lg[5]);
      lg[6] = fmaf(w1.z, hnew[m], lg[6]);
    }
#pragma unroll
    for (int p = 0; p < Pp; p++) {
      lg[p] += __shfl_xor(lg[p], 1);
      lg[p] += __shfl_xor(lg[p], 2);
    }

    // per-lane logits via compile-time select (v_cndmask chain, no reg-array
    // runtime index). Values identical to lg[q]+bh[q], lg[q+4]+bh[q+4].
    float lgq  = ((q == 0) ? lg[0] : (q == 1) ? lg[1] : (q == 2) ? lg[2] : lg[3]) + bh0;
    float lgq4 = ((q == 0) ? lg[4] : (q == 1) ? lg[5] : lg[6]) + bh4;

    // gumbel noise + argmax (tie -> lower index)
    float n1 = -logf(-logf(u1 + 1e-20f) + 1e-20f);
    float bestv = lgq + n1;
    int besti = q;
    if (q < 3) {
      float n2 = -logf(-logf(u2 + 1e-20f) + 1e-20f);
      float v2 = lgq4 + n2;
      if (v2 > bestv) { bestv = v2; besti = q + 4; }
    }
#pragma unroll
    for (int mask = 1; mask <= 2; mask <<= 1) {
      float ov = __shfl_xor(bestv, mask);
      int   oi = __shfl_xor(besti, mask);
      if (ov > bestv || (ov == bestv && oi < besti)) { bestv = ov; besti = oi; }
    }
    kcur = besti;

    // stage outputs in LDS (runtime LDS addressing is fine — it's memory)
    {
      int t8 = (t & 7) * Pp;
      float* sl = &sm[OFF_OUTL + bb * OUT_S + t8];
      float* ss = &sm[OFF_OUTS + bb * OUT_S + t8];
      sl[q] = lgq;
      ss[q] = (besti == q) ? 1.f : 0.f;
      if (q < 3) {
        sl[q + 4] = lgq4;
        ss[q + 4] = (besti == (q + 4)) ? 1.f : 0.f;
      }
    }

    // flush every 8 steps (coalesced 64B-per-quad float4 stores)
    if ((t & 7) == 7) {
      int t0 = t - 7;
#pragma unroll
      for (int i = 0; i < 4; i++) {
        int idx = q + 4 * i;
        if (idx < 14) {
          float4 vL = *(const float4*)&sm[OFF_OUTL + bb * OUT_S + 4 * idx];
          float4 vS = *(const float4*)&sm[OFF_OUTS + bb * OUT_S + 4 * idx];
          *(float4*)&outL[(size_t)t0 * Pp + 4 * idx] = vL;
          *(float4*)&outS[(size_t)t0 * Pp + 4 * idx] = vS;
        }
      }
    } else if (t == T - 1) {
      // generic tail (T not multiple of 8): scalar flush
      int t0 = t & ~7;
      int cnt = (t - t0 + 1) * Pp;
      for (int i = q; i < cnt; i += 4) {
        outL[(size_t)t0 * Pp + i] = sm[OFF_OUTL + bb * OUT_S + i];
        outS[(size_t)t0 * Pp + i] = sm[OFF_OUTS + bb * OUT_S + i];
      }
    }
  }
}

extern "C" void kernel_launch(void* const* d_in, const int* in_sizes, int n_in,
                              void* d_out, int out_size, void* d_ws, size_t ws_size,
                              hipStream_t stream) {
  const float* h_n     = (const float*)d_in[0];
  const float* c_n     = (const float*)d_in[1];
  const float* noise   = (const float*)d_in[2];
  const float* gumbel  = (const float*)d_in[3];
  const float* W_init  = (const float*)d_in[4];
  const float* b_init  = (const float*)d_in[5];
  const float* W_ih    = (const float*)d_in[6];
  const float* W_hh    = (const float*)d_in[7];
  const float* b_ih    = (const float*)d_in[8];
  const float* b_hh    = (const float*)d_in[9];
  const float* W_head  = (const float*)d_in[10];
  const float* b_head  = (const float*)d_in[11];
  const int*   fut_len = (const int*)d_in[12];

  int B = in_sizes[0] / Hh;  // 32768
  dim3 grid((B + 63) / 64), block(256);
  gen_decoder_kernel<<<grid, block, 0, stream>>>(
      h_n, c_n, noise, gumbel, W_init, b_init, W_ih, W_hh, b_ih, b_hh,
      W_head, b_head, fut_len, (float*)d_out, B);
}

// Round 4
// 1914.594 us; speedup vs baseline: 14.8385x; 14.8385x over previous
//
#include <hip/hip_runtime.h>

// GeneratorDecoder: 128-step LSTM (H=32) + gumbel-argmax head (P=7), B=32768.
// Round 4: ONE WAVE PER BATCH ELEMENT. Lane l owns gate rows l and l+64
// (lane pair (j, j+32) covers slot j's i/f/g/o gates; one shfl_xor(32)
// exchange). W_hh lives in VGPRs (64/lane), h broadcast via 32-float LDS
// buffer (wave-uniform ds_read_b128). All FP reduction orders bit-identical
// to the passing rounds 1-3 (gate dot k-ascending, head Sq partials +
// xor1/xor2 tree + bias, same cell/gumbel expression text, same tie-break).

#define Hh 32
#define Pp 7
#define NDd 8
#define WIHB_S 9   // pad 8->9: kcur-uniform reads spread across banks

__global__ __launch_bounds__(64, 2) void gen_decoder_kernel(
    const float* __restrict__ h_n, const float* __restrict__ c_n,
    const float* __restrict__ noise, const float* __restrict__ gumbel_u,
    const float* __restrict__ W_init, const float* __restrict__ b_init,
    const float* __restrict__ W_ih, const float* __restrict__ W_hh,
    const float* __restrict__ b_ih, const float* __restrict__ b_hh,
    const float* __restrict__ W_head, const float* __restrict__ b_head,
    const int* __restrict__ future_len, float* __restrict__ out, int B)
{
  __shared__ __align__(16) float sm_h[Hh];          // current h for this wave's batch
  __shared__ __align__(16) float sm_outL[56];       // 8 steps x 7 logits
  __shared__ __align__(16) float sm_outS[56];       // 8 steps x 7 samples
  __shared__ float sWihB[128 * WIHB_S];             // fused W_ih+biases, col 7 = bias only

  const int l = threadIdx.x;       // 0..63 (block = exactly one wave)
  const int b = blockIdx.x;
  const int T = future_len[0];
  const int j = l & 31;            // state slot (lanes l and l+32 pair on slot j)

  // ---- preamble: fused W_ih/bias table into LDS (wave-local, no barrier) ----
  for (int i = l; i < 128 * WIHB_S; i += 64) {
    int r = i / WIHB_S, p = i - r * WIHB_S;
    if (p < 8) sWihB[i] = b_ih[r] + b_hh[r] + (p < 7 ? W_ih[r * 7 + p] : 0.f);
  }

  // ---- h0 init FIRST (x[40] live range dies before weight regs allocated) ----
  {
    float x[Hh + NDd];
#pragma unroll
    for (int i = 0; i < 8; i++)
      ((float4*)x)[i] = *(const float4*)&h_n[(size_t)b * Hh + 4 * i];
    ((float4*)x)[8] = *(const float4*)&noise[(size_t)b * NDd];
    ((float4*)x)[9] = *(const float4*)&noise[(size_t)b * NDd + 4];
    float a = b_init[j];
    const float* wr = &W_init[j * (Hh + NDd)];
#pragma unroll
    for (int k = 0; k < Hh + NDd; k++) a = fmaf(wr[k], x[k], a);
    if (l < 32) sm_h[j] = a;
  }
  float c = c_n[(size_t)b * Hh + j];

  // ---- recurrent weights into registers: rows rA = l, rB = l + 64 ----
  const int rA = l;        // i-row j (l<32) / f-row j (l>=32)
  const int rB = l + 64;   // g-row j (l<32) / o-row j (l>=32)
  float4 wA4[8], wB4[8];
#pragma unroll
  for (int kc = 0; kc < 8; kc++) {
    wA4[kc] = *(const float4*)&W_hh[rA * Hh + 4 * kc];
    wB4[kc] = *(const float4*)&W_hh[rB * Hh + 4 * kc];
  }

  // head weights: lane 4p+q (p<7) holds W_head[p][q+4m], m=0..7
  const int hp = l >> 2, hq = l & 3;
  float whead[8];
  float bh = 0.f;
  if (l < 28) {
#pragma unroll
    for (int m = 0; m < 8; m++) whead[m] = W_head[hp * Hh + hq + 4 * m];
    bh = b_head[hp];
  } else {
#pragma unroll
    for (int m = 0; m < 8; m++) whead[m] = 0.f;
  }

  int kcur = 7;  // y0 = 0 -> bias-only column
  const size_t strideT = (size_t)B * Pp;
  const float* gu = gumbel_u + (size_t)b * Pp;
  float* outL = out + (size_t)b * T * Pp;
  float* outS = out + (size_t)B * T * Pp + (size_t)b * T * Pp;

  for (int t = 0; t < T; ++t) {
    // gumbel inputs (independent of the recurrence -> issue early)
    const float* ut = gu + (size_t)t * strideT;
    float u1 = 0.f, u2 = 1.f;
    if (l < 4) u1 = ut[l];
    if (l < 3) u2 = ut[l + 4];

    // gate pre-activations: init from fused table (kcur wave-uniform), then
    // k-ascending fmaf chain over h (bit-identical to rounds 1-3)
    float accA = sWihB[rA * WIHB_S + kcur];
    float accB = sWihB[rB * WIHB_S + kcur];
#pragma unroll
    for (int kc = 0; kc < 8; kc++) {
      float4 hv = *(const float4*)&sm_h[4 * kc];   // wave-uniform: LDS broadcast
      float4 wa = wA4[kc], wb = wB4[kc];
      accA = fmaf(wa.x, hv.x, accA);
      accA = fmaf(wa.y, hv.y, accA);
      accA = fmaf(wa.z, hv.z, accA);
      accA = fmaf(wa.w, hv.w, accA);
      accB = fmaf(wb.x, hv.x, accB);
      accB = fmaf(wb.y, hv.y, accB);
      accB = fmaf(wb.z, hv.z, accB);
      accB = fmaf(wb.w, hv.w, accB);
    }

    // lane-pair exchange: (i,g) on lanes <32, (f,o) on lanes >=32
    float xA = __shfl_xor(accA, 32);
    float xB = __shfl_xor(accB, 32);
    float i_pre = (l < 32) ? accA : xA;
    float f_pre = (l < 32) ? xA : accA;
    float g_pre = (l < 32) ? accB : xB;
    float o_pre = (l < 32) ? xB : accB;

    // cell (exact expression text of rounds 1-3)
    float ig = 1.f / (1.f + expf(-i_pre));
    float fg = 1.f / (1.f + expf(-f_pre));
    float gg = tanhf(g_pre);
    float og = 1.f / (1.f + expf(-o_pre));
    float cc = fg * c + ig * gg;
    c = cc;
    float hj = og * tanhf(cc);
    if (l < 32) sm_h[j] = hj;   // in-order DS within the wave: safe

    // head: lane 4p+q computes Sq[p] over m ascending, then xor1/xor2 tree
    // (identical partial/combine shape to rounds 1-3), then +bias
    float lgp = 0.f;
    if (l < 28) {
#pragma unroll
      for (int m = 0; m < 8; m++)
        lgp = fmaf(whead[m], sm_h[hq + 4 * m], lgp);
      lgp += __shfl_xor(lgp, 1);
      lgp += __shfl_xor(lgp, 2);
      lgp += bh;
    }

    // fan logits to lanes 0..3 (bpermute outside divergence: all lanes active)
    float Lq  = __shfl(lgp, 4 * l);        // lane l<4: lg[l]
    float Lq4 = __shfl(lgp, 16 + 4 * l);   // lane l<3: lg[l+4]

    // gumbel noise + argmax on lanes 0..3 (same candidate pairing/tie-break)
    int besti = 0;
    if (l < 4) {
      float n1 = -logf(-logf(u1 + 1e-20f) + 1e-20f);
      float bestv = Lq + n1;
      besti = l;
      if (l < 3) {
        float n2 = -logf(-logf(u2 + 1e-20f) + 1e-20f);
        float v2 = Lq4 + n2;
        if (v2 > bestv) { bestv = v2; besti = l + 4; }  // tie -> lower index
      }
#pragma unroll
      for (int mask = 1; mask <= 2; mask <<= 1) {
        float ov = __shfl_xor(bestv, mask);
        int   oi = __shfl_xor(besti, mask);
        if (ov > bestv || (ov == bestv && oi < besti)) { bestv = ov; besti = oi; }
      }
    }
    kcur = __builtin_amdgcn_readfirstlane(besti);  // lane 0 holds the result

    // stage outputs (lane 4p, p<7 writes logit p and one-hot sample p)
    if (l < 28 && hq == 0) {
      sm_outL[(t & 7) * Pp + hp] = lgp;
      sm_outS[(t & 7) * Pp + hp] = (kcur == hp) ? 1.f : 0.f;
    }

    // flush every 8 steps: 14 lanes x float4 = 224B contiguous per output
    if ((t & 7) == 7) {
      if (l < 14) {
        *(float4*)&outL[(size_t)(t - 7) * Pp + 4 * l] = *(const float4*)&sm_outL[4 * l];
        *(float4*)&outS[(size_t)(t - 7) * Pp + 4 * l] = *(const float4*)&sm_outS[4 * l];
      }
    } else if (t == T - 1) {
      int t0 = t & ~7;
      int cnt = (t - t0 + 1) * Pp;
      for (int i = l; i < cnt; i += 64) {
        outL[(size_t)t0 * Pp + i] = sm_outL[i];
        outS[(size_t)t0 * Pp + i] = sm_outS[i];
      }
    }
  }
}

extern "C" void kernel_launch(void* const* d_in, const int* in_sizes, int n_in,
                              void* d_out, int out_size, void* d_ws, size_t ws_size,
                              hipStream_t stream) {
  const float* h_n     = (const float*)d_in[0];
  const float* c_n     = (const float*)d_in[1];
  const float* noise   = (const float*)d_in[2];
  const float* gumbel  = (const float*)d_in[3];
  const float* W_init  = (const float*)d_in[4];
  const float* b_init  = (const float*)d_in[5];
  const float* W_ih    = (const float*)d_in[6];
  const float* W_hh    = (const float*)d_in[7];
  const float* b_ih    = (const float*)d_in[8];
  const float* b_hh    = (const float*)d_in[9];
  const float* W_head  = (const float*)d_in[10];
  const float* b_head  = (const float*)d_in[11];
  const int*   fut_len = (const int*)d_in[12];

  int B = in_sizes[0] / Hh;  // 32768
  dim3 grid(B), block(64);   // one wave per batch element
  gen_decoder_kernel<<<grid, block, 0, stream>>>(
      h_n, c_n, noise, gumbel, W_init, b_init, W_ih, W_hh, b_ih, b_hh,
      W_head, b_head, fut_len, (float*)d_out, B);
}

// Round 5
// 1392.804 us; speedup vs baseline: 20.3974x; 1.3746x over previous
//
#include <hip/hip_runtime.h>

// GeneratorDecoder: 128-step LSTM (H=32) + gumbel-argmax head (P=7), B=32768.
// Round 5: TWO batch elements per wave (half-wave each). Lane (half, j) owns
// ALL FOUR gate rows of slot j for batch (2*blockIdx + half), as two packed
// v_pk_fma_f32 chains: (i,f) and (g,o). Each row's k-ascending fma chain has
// identical operands/order to rounds 1-4 -> bit-identical trajectory.
// Cell transcendentals / head reduce / gumbel logf / argmax tree / staging are
// issued once per wave-step and now cover 2 batch-steps (2x amortization).

#define Hh 32
#define Pp 7
#define NDd 8

typedef float f32x2 __attribute__((ext_vector_type(2)));

static __device__ __forceinline__ f32x2 fma2(f32x2 w, float h, f32x2 a) {
  return __builtin_elementwise_fma(w, (f32x2){h, h}, a);
}

__global__ __launch_bounds__(64, 2) void gen_decoder_kernel(
    const float* __restrict__ h_n, const float* __restrict__ c_n,
    const float* __restrict__ noise, const float* __restrict__ gumbel_u,
    const float* __restrict__ W_init, const float* __restrict__ b_init,
    const float* __restrict__ W_ih, const float* __restrict__ W_hh,
    const float* __restrict__ b_ih, const float* __restrict__ b_hh,
    const float* __restrict__ W_head, const float* __restrict__ b_head,
    const int* __restrict__ future_len, float* __restrict__ out, int B)
{
  // [col 0..7][row 0..127]: col<7 = W_ih[:,col]+b_ih+b_hh, col 7 = bias only
  __shared__ float sWihB[8 * 128];
  __shared__ __align__(16) float sm_h[2 * 36];   // per-half h, pad 36
  __shared__ __align__(16) float smL[2][56];     // 8 steps x 7 logits per half
  __shared__ __align__(16) float smS[2][56];     // 8 steps x 7 samples per half

  const int l    = threadIdx.x;     // one wave per block
  const int half = l >> 5;          // batch half 0/1
  const int j    = l & 31;          // state slot
  const int b    = blockIdx.x * 2 + half;
  const int T    = future_len[0];

  // fused W_ih/bias table (wave-local: no barrier needed)
  for (int i = l; i < 8 * 128; i += 64) {
    int col = i >> 7, r = i & 127;
    sWihB[i] = b_ih[r] + b_hh[r] + (col < 7 ? W_ih[r * 7 + col] : 0.f);
  }

  // ---- h0 init (x dies before weight registers are allocated) ----
  {
    float x[Hh + NDd];
#pragma unroll
    for (int i = 0; i < 8; i++)
      ((float4*)x)[i] = *(const float4*)&h_n[(size_t)b * Hh + 4 * i];
    ((float4*)x)[8] = *(const float4*)&noise[(size_t)b * NDd];
    ((float4*)x)[9] = *(const float4*)&noise[(size_t)b * NDd + 4];
    float a = b_init[j];
    const float* wr = &W_init[j * (Hh + NDd)];
#pragma unroll
    for (int k = 0; k < Hh + NDd; k++) a = fmaf(wr[k], x[k], a);
    sm_h[half * 36 + j] = a;
  }
  float c = c_n[(size_t)b * Hh + j];

  // ---- recurrent weights into registers: rows {j, 32+j, 64+j, 96+j} ----
  f32x2 wIF[32], wGO[32];
  {
    const float* WI = W_hh + (size_t)(0 * Hh + j) * Hh;
    const float* WF = W_hh + (size_t)(1 * Hh + j) * Hh;
    const float* WG = W_hh + (size_t)(2 * Hh + j) * Hh;
    const float* WO = W_hh + (size_t)(3 * Hh + j) * Hh;
#pragma unroll
    for (int kc = 0; kc < 8; kc++) {
      float4 wi = *(const float4*)&WI[4 * kc];
      float4 wf = *(const float4*)&WF[4 * kc];
      float4 wg = *(const float4*)&WG[4 * kc];
      float4 wo = *(const float4*)&WO[4 * kc];
      wIF[4 * kc + 0] = (f32x2){wi.x, wf.x};
      wIF[4 * kc + 1] = (f32x2){wi.y, wf.y};
      wIF[4 * kc + 2] = (f32x2){wi.z, wf.z};
      wIF[4 * kc + 3] = (f32x2){wi.w, wf.w};
      wGO[4 * kc + 0] = (f32x2){wg.x, wo.x};
      wGO[4 * kc + 1] = (f32x2){wg.y, wo.y};
      wGO[4 * kc + 2] = (f32x2){wg.z, wo.z};
      wGO[4 * kc + 3] = (f32x2){wg.w, wo.w};
    }
  }

  // head weights: within each half, lane 4p+q (p<7) holds W_head[p][q+4m]
  const int hp = (l & 31) >> 2;   // 0..7 (7 = idle)
  const int hq = l & 3;
  float whead[8];
  float bh = 0.f;
  if (hp < 7) {
#pragma unroll
    for (int m = 0; m < 8; m++) whead[m] = W_head[hp * Hh + hq + 4 * m];
    bh = b_head[hp];
  } else {
#pragma unroll
    for (int m = 0; m < 8; m++) whead[m] = 0.f;
  }

  const int r7 = l & 7;   // candidate index within the 8-lane argmax group
  // per-lane gumbel pointer: candidate r7 (clamped) of own batch
  const float* guL = gumbel_u + (size_t)b * Pp + (r7 < 7 ? r7 : 6);
  const size_t strideT = (size_t)B * Pp;

  int kcur = 7;  // y0 = 0 -> bias-only column
  const float* hbase = &sm_h[half * 36];
  float* outL = out + (size_t)b * T * Pp;
  float* outS = out + (size_t)B * T * Pp + (size_t)b * T * Pp;

  for (int t = 0; t < T; ++t) {
    // gumbel input (independent of recurrence -> issue early)
    float uv = guL[(size_t)t * strideT];

    // gate pre-activations: init from fused table, then k-ascending packed
    // fma chains. Each row's scalar chain is bit-identical to rounds 1-4.
    f32x2 accIF, accGO;
    {
      const float* tb = &sWihB[kcur << 7];
      accIF = (f32x2){tb[j], tb[32 + j]};
      accGO = (f32x2){tb[64 + j], tb[96 + j]};
    }
#pragma unroll
    for (int kc = 0; kc < 8; kc++) {
      float4 hv = *(const float4*)&hbase[4 * kc];   // half-uniform: broadcast
      accIF = fma2(wIF[4 * kc + 0], hv.x, accIF);
      accGO = fma2(wGO[4 * kc + 0], hv.x, accGO);
      accIF = fma2(wIF[4 * kc + 1], hv.y, accIF);
      accGO = fma2(wGO[4 * kc + 1], hv.y, accGO);
      accIF = fma2(wIF[4 * kc + 2], hv.z, accIF);
      accGO = fma2(wGO[4 * kc + 2], hv.z, accGO);
      accIF = fma2(wIF[4 * kc + 3], hv.w, accIF);
      accGO = fma2(wGO[4 * kc + 3], hv.w, accGO);
    }

    // cell (exact expression text of rounds 1-4)
    float ig = 1.f / (1.f + expf(-accIF.x));
    float fg = 1.f / (1.f + expf(-accIF.y));
    float gg = tanhf(accGO.x);
    float og = 1.f / (1.f + expf(-accGO.y));
    float cc = fg * c + ig * gg;
    c = cc;
    float hj = og * tanhf(cc);
    sm_h[half * 36 + j] = hj;   // all 64 lanes distinct; in-order within wave

    // head: lane 4p+q partial over m ascending, xor1/xor2 quad tree, + bias
    float lgp = 0.f;
    if (hp < 7) {
#pragma unroll
      for (int m = 0; m < 8; m++)
        lgp = fmaf(whead[m], hbase[hq + 4 * m], lgp);
      lgp += __shfl_xor(lgp, 1);
      lgp += __shfl_xor(lgp, 2);
      lgp += bh;
    }

    // fan logit r7 of own half to this lane (lane 4*r7 of own half holds it)
    float Lr = __shfl(lgp, (l & 32) + 4 * (r7 < 7 ? r7 : 0));

    // gumbel noise (same formula text) + 8-lane lowest-index argmax butterfly
    float nv = -logf(-logf(uv + 1e-20f) + 1e-20f);
    float bestv = (r7 < 7) ? (Lr + nv) : -__builtin_inff();
    int besti = r7;
#pragma unroll
    for (int mask = 1; mask <= 4; mask <<= 1) {
      float ov = __shfl_xor(bestv, mask);
      int   oi = __shfl_xor(besti, mask);
      if (ov > bestv || (ov == bestv && oi < besti)) { bestv = ov; besti = oi; }
    }
    kcur = __shfl(besti, l & 32);   // broadcast own half's result

    // stage outputs (lane 4p, p<7 of each half)
    if (hp < 7 && hq == 0) {
      smL[half][(t & 7) * Pp + hp] = lgp;
      smS[half][(t & 7) * Pp + hp] = (kcur == hp) ? 1.f : 0.f;
    }

    // flush every 8 steps: 14 lanes per half x float4 = 224B contiguous
    if ((t & 7) == 7) {
      int r31 = l & 31;
      if (r31 < 14) {
        *(float4*)&outL[(size_t)(t - 7) * Pp + 4 * r31] = *(const float4*)&smL[half][4 * r31];
        *(float4*)&outS[(size_t)(t - 7) * Pp + 4 * r31] = *(const float4*)&smS[half][4 * r31];
      }
    } else if (t == T - 1) {
      int t0 = t & ~7;
      int cnt = (t - t0 + 1) * Pp;
      for (int i = l & 31; i < cnt; i += 32) {
        outL[(size_t)t0 * Pp + i] = smL[half][i];
        outS[(size_t)t0 * Pp + i] = smS[half][i];
      }
    }
  }
}

extern "C" void kernel_launch(void* const* d_in, const int* in_sizes, int n_in,
                              void* d_out, int out_size, void* d_ws, size_t ws_size,
                              hipStream_t stream) {
  const float* h_n     = (const float*)d_in[0];
  const float* c_n     = (const float*)d_in[1];
  const float* noise   = (const float*)d_in[2];
  const float* gumbel  = (const float*)d_in[3];
  const float* W_init  = (const float*)d_in[4];
  const float* b_init  = (const float*)d_in[5];
  const float* W_ih    = (const float*)d_in[6];
  const float* W_hh    = (const float*)d_in[7];
  const float* b_ih    = (const float*)d_in[8];
  const float* b_hh    = (const float*)d_in[9];
  const float* W_head  = (const float*)d_in[10];
  const float* b_head  = (const float*)d_in[11];
  const int*   fut_len = (const int*)d_in[12];

  int B = in_sizes[0] / Hh;  // 32768
  dim3 grid(B / 2), block(64);   // one wave = two batch elements
  gen_decoder_kernel<<<grid, block, 0, stream>>>(
      h_n, c_n, noise, gumbel, W_init, b_init, W_ih, W_hh, b_ih, b_hh,
      W_head, b_head, fut_len, (float*)d_out, B);
}